// Round 26
// baseline (55.810 us; speedup 1.0000x reference)
//
#include <hip/hip_runtime.h>
#include <hip/hip_bf16.h>

#define NSEQ 2048
#define DD   64
#define HH   16
#define QT   128
#define KVB  64
#define NKV  (NSEQ / KVB)
#define NR   (NKV / 2)

typedef __attribute__((ext_vector_type(4)))  float f4;
typedef __attribute__((ext_vector_type(16))) float f32x16;
typedef __attribute__((ext_vector_type(8)))  short bf16x8;
typedef __attribute__((ext_vector_type(4)))  unsigned int u32x4;
typedef __attribute__((ext_vector_type(2)))  unsigned int u32x2;

#define QSCL  0.36067376022224085f  /* 2*scale*log2e = 0.25*log2(e); K stays raw */
#define LOG2E 1.4426950408889634f
#define NEGBIG (-1.0e30f)

/* K tile swizzle: slot = q ^ (row&7) — store 8-spread, read 8-spread */
#define SWZ(row, q)  (((row) << 6) + ((((q) ^ ((row) & 7))) << 3))
/* V tile swizzle: slot = q ^ ((d>>2)&7) ^ (d&3) — store 8-spread (dq fast), read 2-way */
#define SWZV(d, q)   (((d) << 6) + ((((q) ^ (((d) >> 2) & 7) ^ ((d) & 3))) << 3))

#if defined(__has_builtin)
#if __has_builtin(__builtin_amdgcn_exp2f)
#define EXP2F __builtin_amdgcn_exp2f
#endif
#if __has_builtin(__builtin_amdgcn_permlane32_swap)
#define HAVE_PLSWAP 1
#endif
#endif
#ifndef EXP2F
#define EXP2F exp2f
#endif

union bfu { u32x4 u; bf16x8 h; };

__device__ __forceinline__ unsigned cvtpk(float lo, float hi) {
    unsigned r;
    asm("v_cvt_pk_bf16_f32 %0, %1, %2" : "=v"(r) : "v"(lo), "v"(hi));
    return r;
}
template<int CTRL>
__device__ __forceinline__ float dppf(float x) {
    return __int_as_float(__builtin_amdgcn_update_dpp(
        0, __float_as_int(x), CTRL, 0xF, 0xF, true));
}
/* cross-half (lane ^ 32) add — direction-robust: combine BOTH outputs */
__device__ __forceinline__ float cross_add(float x) {
#ifdef HAVE_PLSWAP
    u32x2 r = __builtin_amdgcn_permlane32_swap(__float_as_uint(x), __float_as_uint(x),
                                               false, false);
    return __uint_as_float(r[0]) + __uint_as_float(r[1]);
#else
    return x + __shfl_xor(x, 32);
#endif
}
/* PV-pack pair build: returns d0 = {A.lo, B.lo}, d2 = {A.hi, B.hi}. (R13-verified) */
__device__ __forceinline__ void pairmix(unsigned A, unsigned B,
                                        unsigned& d0, unsigned& d2, bool hi) {
#ifdef HAVE_PLSWAP
    u32x2 r = __builtin_amdgcn_permlane32_swap(A, B, false, false);
    d0 = r[0]; d2 = r[1];
#else
    unsigned v = hi ? A : B;
    unsigned x = (unsigned)__shfl_xor((int)v, 32);
    d0 = hi ? x : A;
    d2 = hi ? B : x;
#endif
}

__global__ __launch_bounds__(256, 2)
void attend_kernel(const float* __restrict__ qg, const float* __restrict__ kg,
                   const float* __restrict__ vg, const int* __restrict__ maskg,
                   float* __restrict__ outg)
{
    /* pair-buffers: round r computes pair p=r&1, stages pair p^1. 66,560 B. */
    __shared__ __align__(16) unsigned short Ks[2][2 * KVB * DD];  /* 32 KB */
    __shared__ __align__(16) unsigned short Vt[2][2 * KVB * DD];  /* 32 KB */
    __shared__ __align__(16) float bias_s[2][2 * KVB];            /*  1 KB */

    const int t    = threadIdx.x;
    const int w    = t >> 6;
    const int lane = t & 63;
    const int c5   = lane & 31;
    const int g2   = lane >> 5;

    /* XCD-aware swizzle: 16 q-tiles of one head stay on one XCD */
    const int p0    = blockIdx.x;
    const int bh    = (p0 & 7) * 4 + ((p0 >> 3) >> 4);
    const int qtile = (p0 >> 3) & 15;
    const int b     = bh >> 4;

    const size_t base = (size_t)bh * NSEQ * DD;
    const float* kp = kg + base;
    const float* vp = vg + base;
    const int*   mp = maskg + b * NSEQ;

    /* Q B-fragments, scaled by full 2*scale*log2e (K stays raw) */
    bfu qf[4];
    {
        const float* qp = qg + base + (size_t)(qtile*QT + w*32 + c5) * DD;
        #pragma unroll
        for (int ck = 0; ck < 4; ++ck) {
            f4 a  = *(const f4*)(qp + ck*16 + g2*8);
            f4 bb = *(const f4*)(qp + ck*16 + g2*8 + 4);
            qf[ck].u = (u32x4){ cvtpk(a[0]*QSCL,  a[1]*QSCL),  cvtpk(a[2]*QSCL,  a[3]*QSCL),
                                cvtpk(bb[0]*QSCL, bb[1]*QSCL), cvtpk(bb[2]*QSCL, bb[3]*QSCL) };
        }
    }

    /* separate accumulators for even/odd tiles — summed once in the epilogue */
    f32x16 aA0, aA1, aB0, aB1;
    #pragma unroll
    for (int r = 0; r < 16; ++r) { aA0[r]=0.f; aA1[r]=0.f; aB0[r]=0.f; aB1[r]=0.f; }
    float l_run = 0.f;   /* per-half partial; combined once at epilogue */

    /* staging roles: waves 0-1 -> K (+bias), waves 2-3 -> V (transpose) */
    const bool isK = (w < 2);
    const int  jK  = t >> 1;          /* K row, t<128 */
    const int  kq0 = (t & 1) * 4;     /* K 16B-quad base (d-half) */
    const int  uv  = t & 127;
    const int  dq  = uv & 15;         /* V d-quad — fast-varying: coalesced global */
    const int  jq  = uv >> 4;         /* V col-octet */

    f4  st[8];
    int mr = 0;

    auto loadTile = [&](int gt) {
        const int j0 = gt * KVB;
        if (isK) {
            const float* src = kp + (size_t)(j0 + jK) * DD + kq0 * 8;
            #pragma unroll
            for (int i2 = 0; i2 < 8; ++i2) st[i2] = ((const f4*)src)[i2];
            mr = mp[j0 + jK];
        } else {
            #pragma unroll
            for (int i2 = 0; i2 < 8; ++i2)
                st[i2] = *(const f4*)(vp + (size_t)(j0 + jq*8 + i2) * DD + dq*4);
        }
    };

    auto stageTile = [&](int pbuf, int tsub) {
        if (isK) {
            float sq = 0.f;
            #pragma unroll
            for (int i2 = 0; i2 < 8; ++i2)
                sq += st[i2][0]*st[i2][0] + st[i2][1]*st[i2][1]
                    + st[i2][2]*st[i2][2] + st[i2][3]*st[i2][3];
            sq += dppf<0xB1>(sq);                   /* pair (xor1) reduce */
            if ((t & 1) == 0) bias_s[pbuf][tsub*KVB + jK] = (mr > 0) ? NEGBIG : -sq * LOG2E;
            #pragma unroll
            for (int s2 = 0; s2 < 4; ++s2) {
                u32x4 kk = (u32x4){ cvtpk(st[2*s2][0],   st[2*s2][1]),
                                    cvtpk(st[2*s2][2],   st[2*s2][3]),
                                    cvtpk(st[2*s2+1][0], st[2*s2+1][1]),
                                    cvtpk(st[2*s2+1][2], st[2*s2+1][3]) };
                *(u32x4*)&Ks[pbuf][tsub*(KVB*DD) + SWZ(jK, kq0 + s2)] = kk;
            }
        } else {
            #pragma unroll
            for (int cc = 0; cc < 4; ++cc) {
                int d = dq*4 + cc;
                u32x4 tv = (u32x4){ cvtpk(st[0][cc], st[1][cc]),
                                    cvtpk(st[2][cc], st[3][cc]),
                                    cvtpk(st[4][cc], st[5][cc]),
                                    cvtpk(st[6][cc], st[7][cc]) };
                *(u32x4*)&Vt[pbuf][tsub*(KVB*DD) + SWZV(d, jq)] = tv;
            }
        }
    };

    /* prologue: tiles 0,1 -> pair-buffer 0; tile 2 loads in flight */
    loadTile(0); stageTile(0, 0);
    loadTile(1); stageTile(0, 1);
    loadTile(2);
    __syncthreads();

    /* max-free QK^T: L2-distance scores <= 0, fixed softmax base m = 0 */
    auto qkt = [&](int p, int tsub, f32x16* sOut) {
        #pragma unroll
        for (int jt = 0; jt < 2; ++jt) {
            f4 b4[4];
            #pragma unroll
            for (int q = 0; q < 4; ++q)
                b4[q] = *(const f4*)&bias_s[p][tsub*KVB + 32*jt + 8*q + 4*g2];
            f32x16 sc;
            #pragma unroll
            for (int rr = 0; rr < 16; ++rr) sc[rr] = b4[rr>>2][rr&3];
            __builtin_amdgcn_s_setprio(1);
            #pragma unroll
            for (int ck = 0; ck < 4; ++ck) {
                bfu kb;
                kb.u = *(const u32x4*)&Ks[p][tsub*(KVB*DD) + SWZ(32*jt + c5, 2*ck + g2)];
                sc = __builtin_amdgcn_mfma_f32_32x32x16_bf16(kb.h, qf[ck].h, sc, 0, 0, 0);
            }
            __builtin_amdgcn_s_setprio(0);
            sOut[jt] = sc;
        }
    };
    auto packP = [&](const f32x16* s01, unsigned* Wp) {
        float ls0 = 0.f, ls1 = 0.f;
        #pragma unroll
        for (int jt = 0; jt < 2; ++jt) {
            #pragma unroll
            for (int m = 0; m < 8; ++m) {
                float e0 = EXP2F(s01[jt][2*m]);
                float e1 = EXP2F(s01[jt][2*m+1]);
                if (m & 1) ls1 += e0 + e1; else ls0 += e0 + e1;
                Wp[jt*8 + m] = cvtpk(e0, e1);
            }
        }
        l_run += ls0 + ls1;
    };
    const bool hi = (g2 != 0);
    auto pv = [&](int p, int tsub, const unsigned* Wp, f32x16& o0, f32x16& o1) {
        __builtin_amdgcn_s_setprio(1);
        #pragma unroll
        for (int ck = 0; ck < 4; ++ck) {
            const int bs = (ck >> 1) * 8 + 4 * (ck & 1);
            unsigned d00, d20, d01, d21;
            pairmix(Wp[bs],   Wp[bs+2], d00, d20, hi);
            pairmix(Wp[bs+1], Wp[bs+3], d01, d21, hi);
            bfu pb;
            pb.u = (u32x4){ d00, d01, d20, d21 };
            bfu va0, va1;
            va0.u = *(const u32x4*)&Vt[p][tsub*(KVB*DD) + SWZV(     c5, 2*ck + g2)];
            va1.u = *(const u32x4*)&Vt[p][tsub*(KVB*DD) + SWZV(32 + c5, 2*ck + g2)];
            o0 = __builtin_amdgcn_mfma_f32_32x32x16_bf16(va0.h, pb.h, o0, 0, 0, 0);
            o1 = __builtin_amdgcn_mfma_f32_32x32x16_bf16(va1.h, pb.h, o1, 0, 0, 0);
        }
        __builtin_amdgcn_s_setprio(0);
    };

    for (int r = 0; r < NR; ++r) {
        const int p = r & 1;

        /* early: stage tile 2r+2 (loaded last round), issue load 2r+3 */
        if (r + 1 < NR) { stageTile(p ^ 1, 0); loadTile(2*r + 3); }

        /* staggered independent pipelines for the two tiles */
        unsigned WpA[16], WpB[16];
        {
            f32x16 sA[2];
            qkt(p, 0, sA);
            packP(sA, WpA);
        }
        {
            f32x16 sB[2];
            qkt(p, 1, sB);   /* overlaps packA's VALU work */
            packP(sB, WpB);
        }

        /* late: stage tile 2r+3 (HBM latency covered by compute), issue 2r+4 */
        if (r + 1 < NR) { stageTile(p ^ 1, 1); if (r + 2 < NR) loadTile(2*r + 4); }

        pv(p, 0, WpA, aA0, aA1);
        pv(p, 1, WpB, aB0, aB1);

        /* raw barrier: drain LDS ops only (stage-writes visible, buffer-p reads
           retired); global prefetch loads stay IN FLIGHT across the barrier —
           the compiler's counted vmcnt waits at next round's stageTile are the
           only consumer-side waits. (No sched_barrier pinning, no reg copies —
           the two confounds that sank the R12 attempt.) */
        asm volatile("s_waitcnt lgkmcnt(0)" ::: "memory");
        __builtin_amdgcn_s_barrier();
    }

    /* epilogue: merge even/odd accs, combine per-half l, normalize, store */
    l_run = cross_add(l_run);
    float inv = 1.0f / l_run;
    float* op = outg + base + (size_t)(qtile*QT + w*32 + c5) * DD;
    #pragma unroll
    for (int dt = 0; dt < 2; ++dt) {
        const f32x16 A = dt ? aA1 : aA0;
        const f32x16 B = dt ? aB1 : aB0;
        #pragma unroll
        for (int q = 0; q < 4; ++q) {
            f4 o = { (A[4*q]  +B[4*q]  )*inv, (A[4*q+1]+B[4*q+1])*inv,
                     (A[4*q+2]+B[4*q+2])*inv, (A[4*q+3]+B[4*q+3])*inv };
            *(f4*)(op + 32*dt + 8*q + 4*g2) = o;
        }
    }
}

extern "C" void kernel_launch(void* const* d_in, const int* in_sizes, int n_in,
                              void* d_out, int out_size, void* d_ws, size_t ws_size,
                              hipStream_t stream) {
    const float* q    = (const float*)d_in[0];
    const float* k    = (const float*)d_in[1];
    const float* v    = (const float*)d_in[2];
    const int*   mask = (const int*)d_in[3];
    float* out = (float*)d_out;
    attend_kernel<<<dim3(512), dim3(256), 0, stream>>>(q, k, v, mask, out);
}